// Round 5
// baseline (237.614 us; speedup 1.0000x reference)
//
#include <hip/hip_runtime.h>
#include <hip/hip_cooperative_groups.h>
#include <stdint.h>

// Problem constants (from reference)
#define BATCH 1024
#define FEAT  784
#define OUTF  1024
#define OR_T  32
#define AND_T 16
#define NIDX  1569          // 1 + 2*FEAT boolean input columns
#define BSTRIDE 1600        // padded u64 words per batch-group bit column
#define NGROUP  16          // BATCH / 64
#define TKDIM   512         // OR_T * AND_T flattened (term,k) extent
#define WPAD    257         // padded u32 row stride for widx[o][tk/2]

#define WS_NEED ((size_t)NGROUP * BSTRIDE * 8)   // 204,800 B (bits only)

typedef unsigned long long u64;
typedef __attribute__((ext_vector_type(2))) u64 u64x2;   // 16B

namespace cg = cooperative_groups;

// ---------------------------------------------------------------------------
// Single cooperative kernel: 1024 blocks x 256 threads, 2 dispatches/iter
// total (harness ws-poison fill + this). Replaces prep+eval (3 dispatches):
// the ~12 us of inter-dispatch overhead was the largest controllable cost.
//
//  widx stage: block (g,ob,q) stages its 32 KB natural-layout w slice
//    (16 outputs x 512 tk ints, contiguous, coalesced int4) into LDS as u16
//    index pairs widx[o][tk/2] (pad 257 -> eval reads are 2-way = free).
//    Deletes prep's transpose kernel half and the 2 MB wt ws roundtrip.
//  pack phase: 3136 wave-units (g, f4) over 4096 waves; lane = batch row,
//    one scattered float4 + 4 ballots + <=4-lane stores into bits[g] (ws).
//    Grid-parallel: ~1 memory roundtrip total vs 7 serialized in prep.
//  grid.sync (threadfence first), then eval3's verified logic: stage the
//    12.8 KB bit table, 32 random ds_read_b64 gathers + or_mask per thread,
//    LDS OR-reduce over 16 term-groups, 4 coalesced int32 stores.
//
// Occupancy: LDS 12.8+16.4+2 = 31.3 KB -> 5 blocks/CU >= 4 required for
// 1024-block co-residency. XCD swizzle keyed on ob (2x128KB w slice L2-hot).
// ---------------------------------------------------------------------------
__global__ __launch_bounds__(256) void fusedc(const float* __restrict__ x,
                                              const int* __restrict__ w,
                                              u64* __restrict__ bits,
                                              int* __restrict__ out) {
    __shared__ __align__(16) u64 lbits[BSTRIDE];   // 12.8 KB
    __shared__ unsigned int widx[16 * WPAD];       // 16.4 KB
    __shared__ u64 red[256];                       // 2 KB

    const int bid  = blockIdx.x;
    const int tid  = threadIdx.x;
    const int lane = tid & 63;
    const int wv   = tid >> 6;              // wave 0..3

    // eval decode (needed now for widx staging)
    const int xcd = bid & 7;
    const int s   = bid >> 3;               // 0..127
    const int ob  = xcd + 8 * (s & 1);      // 0..15, 2 per XCD
    const int q   = (s >> 1) & 3;           // quarter 0..3
    const int g   = s >> 3;                 // 0..15

    // ---- stage widx: 32 KB contiguous w slice -> LDS u16 pairs ----
    const int4* wsrc = (const int4*)(w + (size_t)(ob * 64 + q * 16) * TKDIM);
    #pragma unroll
    for (int t = 0; t < 8; ++t) {
        const int q4 = t * 256 + tid;       // int4 index 0..2047
        const int4 v = wsrc[q4];
        const int o  = q4 >> 7;             // output row 0..15 (128 int4/row)
        const int r  = (q4 & 127) * 2;      // packed-pair index (even)
        widx[o * WPAD + r] =
            ((unsigned int)v.x & 0xFFFFu) | ((unsigned int)v.y << 16);
        widx[o * WPAD + r + 1] =
            ((unsigned int)v.z & 0xFFFFu) | ((unsigned int)v.w << 16);
    }

    // ---- pack phase: wave-unit u = (g, f4); wave-uniform predicate ----
    const int u = wv * 1024 + bid;          // 0..4095; 3136 active
    if (u < 3136) {
        const int pg = u / 196;             // batch group 0..15
        const int f4 = u % 196;             // float4 column-group
        const float4 v = *(const float4*)(x + (size_t)(pg * 64 + lane) * FEAT
                                            + f4 * 4);
        u64* bg = bits + (size_t)pg * BSTRIDE;
        const u64 m0 = __ballot(v.x != 0.0f);
        const u64 m1 = __ballot(v.y != 0.0f);
        const u64 m2 = __ballot(v.z != 0.0f);
        const u64 m3 = __ballot(v.w != 0.0f);
        const u64 mv = (lane == 0) ? m0 : (lane == 1) ? m1 : (lane == 2) ? m2 : m3;
        const int f = f4 * 4;
        if (lane < 4) {
            bg[1 + f + lane]   = mv;
            bg[785 + f + lane] = ~mv;
        }
        if (f4 == 0 && lane == 4) bg[0] = ~0ull;
    }

    __threadfence();
    cg::this_grid().sync();

    // ---- stage the group's bit table from ws ----
    const u64* bg2 = bits + (size_t)g * BSTRIDE;
    #pragma unroll
    for (int i = 0; i < 4; ++i) {
        const int t = i * 256 + tid;
        if (t < BSTRIDE / 2) ((u64x2*)lbits)[t] = ((const u64x2*)bg2)[t];
    }
    __syncthreads();

    // ---- eval: 2 OR-terms per thread (verified fused2/eval3 math) ----
    const int ol = tid & 15;
    const int tg = tid >> 4;                // term-group 0..15

    u64 orv = 0;
    #pragma unroll
    for (int tt = 0; tt < 2; ++tt) {
        const int term = tg * 2 + tt;
        const unsigned int* wr = widx + ol * WPAD + term * 8;
        u64 a = ~0ull;
        unsigned int zor = 0;               // OR of the 16 indices (or_mask)
        #pragma unroll
        for (int kk = 0; kk < 8; ++kk) {
            const unsigned int pk = wr[kk];
            zor |= pk;
            a &= lbits[pk & 0xFFFFu];
            a &= lbits[pk >> 16];
        }
        if (zor != 0) orv |= a;             // all-zero term is masked off
    }

    red[tid] = orv;
    __syncthreads();

    u64 full = 0;
    #pragma unroll
    for (int j = 0; j < 16; ++j) full |= red[j * 16 + ol];

    int* outg = out + (size_t)(g * 64) * OUTF + (size_t)ob * 64 + q * 16;
    #pragma unroll
    for (int jj = 0; jj < 4; ++jj) {
        const int j = tg * 4 + jj;
        outg[(size_t)j * OUTF + ol] = (int)((full >> j) & 1);
    }
}

// ---------------------------------------------------------------------------
// Fallback: fully fused if ws is too small. Same math (verified baseline).
// ---------------------------------------------------------------------------
__global__ __launch_bounds__(1024) void binlayer_fused(const float* __restrict__ x,
                                                       const int* __restrict__ w,
                                                       int* __restrict__ out) {
    __shared__ u64 lbits[BSTRIDE];
    __shared__ u64 red[1024];

    const int g    = blockIdx.x;
    const int ob   = blockIdx.y;
    const int tid  = threadIdx.x;
    const int lane = tid & 63;
    const int wv   = tid >> 6;

    const int start = wv * 12 + (wv < 4 ? wv : 4);
    const int cnt   = (wv < 4) ? 13 : 12;
    const float4* xrow = (const float4*)(x + (size_t)(g * 64 + lane) * FEAT);
    for (int i = 0; i < cnt; ++i) {
        const int f4 = start + i;
        const float4 v = xrow[f4];
        const int f = f4 * 4;
        const u64 m0 = __ballot(v.x != 0.0f);
        const u64 m1 = __ballot(v.y != 0.0f);
        const u64 m2 = __ballot(v.z != 0.0f);
        const u64 m3 = __ballot(v.w != 0.0f);
        const u64 mv = (lane == 0) ? m0 : (lane == 1) ? m1 : (lane == 2) ? m2 : m3;
        if (lane < 4) {
            lbits[1 + f + lane]   = mv;
            lbits[785 + f + lane] = ~mv;
        }
    }
    if (tid == 0) lbits[0] = ~0ull;
    __syncthreads();

    const int o_local = tid & 63;
    const int tg      = tid >> 6;
    const int o       = ob * 64 + o_local;
    const int4* wq = (const int4*)(w + ((size_t)o * OR_T + tg * 2) * AND_T);

    u64 orv = 0;
    #pragma unroll
    for (int tt = 0; tt < 2; ++tt) {
        u64 a = ~0ull;
        int zor = 0;
        #pragma unroll
        for (int k = 0; k < 4; ++k) {
            const int4 wi = wq[tt * 4 + k];
            zor |= wi.x | wi.y | wi.z | wi.w;
            a &= lbits[wi.x];
            a &= lbits[wi.y];
            a &= lbits[wi.z];
            a &= lbits[wi.w];
        }
        if (zor != 0) orv |= a;
    }

    red[tid] = orv;
    __syncthreads();

    u64 full = 0;
    #pragma unroll
    for (int j = 0; j < 16; ++j) full |= red[o_local + j * 64];

    int* outg = out + (size_t)(g * 64) * OUTF + (size_t)ob * 64;
    #pragma unroll
    for (int jj = 0; jj < 4; ++jj) {
        const int j = tg * 4 + jj;
        outg[(size_t)j * OUTF + o_local] = (int)((full >> j) & 1);
    }
}

extern "C" void kernel_launch(void* const* d_in, const int* in_sizes, int n_in,
                              void* d_out, int out_size, void* d_ws, size_t ws_size,
                              hipStream_t stream) {
    (void)in_sizes; (void)n_in;
    const float* x = (const float*)d_in[0];   // (1024, 784) float32 of 0/1
    const int*   w = (const int*)d_in[1];     // (1024, 32, 16) int32 in [0,1569)
    int* out = (int*)d_out;                   // (1024, 1024) bool -> int32

    if (ws_size >= WS_NEED) {
        u64* bits = (u64*)d_ws;
        void* args[] = {(void*)&x, (void*)&w, (void*)&bits, (void*)&out};
        hipLaunchCooperativeKernel((const void*)fusedc, dim3(1024), dim3(256),
                                   args, 0, stream);
    } else {
        binlayer_fused<<<dim3(NGROUP, OUTF / 64), 1024, 0, stream>>>(x, w, out);
    }
}

// Round 6
// 65.988 us; speedup vs baseline: 3.6008x; 3.6008x over previous
//
#include <hip/hip_runtime.h>
#include <stdint.h>

// Problem constants (from reference)
#define BATCH 1024
#define FEAT  784
#define OUTF  1024
#define OR_T  32
#define AND_T 16
#define NIDX  1569          // 1 + 2*FEAT boolean input columns
#define BSTRIDE 1600        // padded u64 words per batch-group bit column
#define NGROUP  16          // BATCH / 64
#define TKDIM   512         // OR_T * AND_T flattened (term,k) extent
#define WPAD    257         // padded u32 row stride for widx[o][tk/2]

#define WS_NEED ((size_t)NGROUP * BSTRIDE * 8)   // 204,800 B (bits only)

#define NB_PACK 3136        // 16 groups x 196 float4 column-units

typedef unsigned long long u64;
typedef __attribute__((ext_vector_type(2))) u64 u64x2;   // 16B

// ---------------------------------------------------------------------------
// pack: grid-parallel ballot transpose of x -> bits (ws). One 64-thread
// block per (group, float4-column) unit: 1 scattered float4 load (lane =
// batch row), 4 ballots, <=4-lane stores. 3136 blocks ~ 12 blocks/CU ->
// all loads in flight at once (~1 memory roundtrip grid-wide) vs the
// previous 448-block/7-iter prep at 2.25 waves/CU. Math verified in
// round-5's fusedc (absmax 0). The w-transpose is gone: eval now stages
// w directly from its natural layout.
// ---------------------------------------------------------------------------
__global__ __launch_bounds__(64) void pack(const float* __restrict__ x,
                                           u64* __restrict__ bits) {
    const int bid = blockIdx.x;
    const int tid = threadIdx.x;
    const int pg  = bid / 196;              // batch group 0..15
    const int f4  = bid % 196;              // float4 column-group 0..195

    const float4 v = *(const float4*)(x + (size_t)(pg * 64 + tid) * FEAT
                                        + f4 * 4);
    u64* bg = bits + (size_t)pg * BSTRIDE;
    const u64 m0 = __ballot(v.x != 0.0f);
    const u64 m1 = __ballot(v.y != 0.0f);
    const u64 m2 = __ballot(v.z != 0.0f);
    const u64 m3 = __ballot(v.w != 0.0f);
    const u64 mv = (tid == 0) ? m0 : (tid == 1) ? m1 : (tid == 2) ? m2 : m3;
    const int f = f4 * 4;
    if (tid < 4) {
        bg[1 + f + tid]   = mv;
        bg[785 + f + tid] = ~mv;
    }
    if (f4 == 0 && tid == 4) bg[0] = ~0ull;
}

// ---------------------------------------------------------------------------
// eval: 1024 blocks x 256 threads (LDS 31.3 KB -> 5 blocks/CU, 20 waves).
// Block (g, ob, q) = 16 outputs. Stages its contiguous 32 KB natural-layout
// w slice into LDS u16 pairs widx[o][tk/2] (pad 257: writes and reads both
// 2-way banked = free) and the group's 12.8 KB bit table; thread (tg, ol)
// evaluates 2 OR-terms (16 LDS index reads + 32 random ds_read_b64 gathers,
// or_mask via zor); LDS OR-reduce over 16 term-groups; 4 coalesced int32
// stores. XCD swizzle: each XCD sees ob in {xcd, xcd+8} -> its w slices and
// x-group bit tables stay L2-hot. Math verified in round-5's fusedc.
// ---------------------------------------------------------------------------
__global__ __launch_bounds__(256) void eval4(const float* __restrict__ x,
                                             const int* __restrict__ w,
                                             const u64* __restrict__ bits,
                                             int* __restrict__ out) {
    __shared__ __align__(16) u64 lbits[BSTRIDE];   // 12.8 KB
    __shared__ unsigned int widx[16 * WPAD];       // 16.4 KB
    __shared__ u64 red[256];                       // 2 KB

    const int bid = blockIdx.x;
    const int tid = threadIdx.x;

    const int xcd = bid & 7;
    const int s   = bid >> 3;               // 0..127
    const int ob  = xcd + 8 * (s & 1);      // 0..15, 2 per XCD
    const int q   = (s >> 1) & 3;           // quarter 0..3
    const int g   = s >> 3;                 // 0..15

    // ---- stage widx: 32 KB contiguous w slice -> LDS u16 pairs ----
    const int4* wsrc = (const int4*)(w + (size_t)(ob * 64 + q * 16) * TKDIM);
    #pragma unroll
    for (int t = 0; t < 8; ++t) {
        const int q4 = t * 256 + tid;       // int4 index 0..2047
        const int4 v = wsrc[q4];
        const int o  = q4 >> 7;             // output row 0..15 (128 int4/row)
        const int r  = (q4 & 127) * 2;      // packed-pair index (even)
        widx[o * WPAD + r] =
            ((unsigned int)v.x & 0xFFFFu) | ((unsigned int)v.y << 16);
        widx[o * WPAD + r + 1] =
            ((unsigned int)v.z & 0xFFFFu) | ((unsigned int)v.w << 16);
    }

    // ---- stage the group's bit table from ws ----
    const u64* bg = bits + (size_t)g * BSTRIDE;
    #pragma unroll
    for (int i = 0; i < 4; ++i) {
        const int t = i * 256 + tid;
        if (t < BSTRIDE / 2) ((u64x2*)lbits)[t] = ((const u64x2*)bg)[t];
    }
    __syncthreads();

    // ---- eval: 2 OR-terms per thread ----
    const int ol = tid & 15;
    const int tg = tid >> 4;                // term-group 0..15

    u64 orv = 0;
    #pragma unroll
    for (int tt = 0; tt < 2; ++tt) {
        const int term = tg * 2 + tt;
        const unsigned int* wr = widx + ol * WPAD + term * 8;
        u64 a = ~0ull;
        unsigned int zor = 0;               // OR of the 16 indices (or_mask)
        #pragma unroll
        for (int kk = 0; kk < 8; ++kk) {
            const unsigned int pk = wr[kk];
            zor |= pk;
            a &= lbits[pk & 0xFFFFu];
            a &= lbits[pk >> 16];
        }
        if (zor != 0) orv |= a;             // all-zero term is masked off
    }

    red[tid] = orv;
    __syncthreads();

    u64 full = 0;
    #pragma unroll
    for (int j = 0; j < 16; ++j) full |= red[j * 16 + ol];

    int* outg = out + (size_t)(g * 64) * OUTF + (size_t)ob * 64 + q * 16;
    #pragma unroll
    for (int jj = 0; jj < 4; ++jj) {
        const int j = tg * 4 + jj;
        outg[(size_t)j * OUTF + ol] = (int)((full >> j) & 1);
    }
    (void)x;
}

// ---------------------------------------------------------------------------
// Fallback: fully fused if ws is too small. Same math (verified baseline).
// ---------------------------------------------------------------------------
__global__ __launch_bounds__(1024) void binlayer_fused(const float* __restrict__ x,
                                                       const int* __restrict__ w,
                                                       int* __restrict__ out) {
    __shared__ u64 lbits[BSTRIDE];
    __shared__ u64 red[1024];

    const int g    = blockIdx.x;
    const int ob   = blockIdx.y;
    const int tid  = threadIdx.x;
    const int lane = tid & 63;
    const int wv   = tid >> 6;

    const int start = wv * 12 + (wv < 4 ? wv : 4);
    const int cnt   = (wv < 4) ? 13 : 12;
    const float4* xrow = (const float4*)(x + (size_t)(g * 64 + lane) * FEAT);
    for (int i = 0; i < cnt; ++i) {
        const int f4 = start + i;
        const float4 v = xrow[f4];
        const int f = f4 * 4;
        const u64 m0 = __ballot(v.x != 0.0f);
        const u64 m1 = __ballot(v.y != 0.0f);
        const u64 m2 = __ballot(v.z != 0.0f);
        const u64 m3 = __ballot(v.w != 0.0f);
        const u64 mv = (lane == 0) ? m0 : (lane == 1) ? m1 : (lane == 2) ? m2 : m3;
        if (lane < 4) {
            lbits[1 + f + lane]   = mv;
            lbits[785 + f + lane] = ~mv;
        }
    }
    if (tid == 0) lbits[0] = ~0ull;
    __syncthreads();

    const int o_local = tid & 63;
    const int tg      = tid >> 6;
    const int o       = ob * 64 + o_local;
    const int4* wq = (const int4*)(w + ((size_t)o * OR_T + tg * 2) * AND_T);

    u64 orv = 0;
    #pragma unroll
    for (int tt = 0; tt < 2; ++tt) {
        u64 a = ~0ull;
        int zor = 0;
        #pragma unroll
        for (int k = 0; k < 4; ++k) {
            const int4 wi = wq[tt * 4 + k];
            zor |= wi.x | wi.y | wi.z | wi.w;
            a &= lbits[wi.x];
            a &= lbits[wi.y];
            a &= lbits[wi.z];
            a &= lbits[wi.w];
        }
        if (zor != 0) orv |= a;
    }

    red[tid] = orv;
    __syncthreads();

    u64 full = 0;
    #pragma unroll
    for (int j = 0; j < 16; ++j) full |= red[o_local + j * 64];

    int* outg = out + (size_t)(g * 64) * OUTF + (size_t)ob * 64;
    #pragma unroll
    for (int jj = 0; jj < 4; ++jj) {
        const int j = tg * 4 + jj;
        outg[(size_t)j * OUTF + o_local] = (int)((full >> j) & 1);
    }
}

extern "C" void kernel_launch(void* const* d_in, const int* in_sizes, int n_in,
                              void* d_out, int out_size, void* d_ws, size_t ws_size,
                              hipStream_t stream) {
    (void)in_sizes; (void)n_in;
    const float* x = (const float*)d_in[0];   // (1024, 784) float32 of 0/1
    const int*   w = (const int*)d_in[1];     // (1024, 32, 16) int32 in [0,1569)
    int* out = (int*)d_out;                   // (1024, 1024) bool -> int32

    if (ws_size >= WS_NEED) {
        u64* bits = (u64*)d_ws;
        pack<<<NB_PACK, 64, 0, stream>>>(x, bits);
        eval4<<<1024, 256, 0, stream>>>(x, w, bits, out);
    } else {
        binlayer_fused<<<dim3(NGROUP, OUTF / 64), 1024, 0, stream>>>(x, w, out);
    }
}